// Round 10
// baseline (197.602 us; speedup 1.0000x reference)
//
#include <hip/hip_runtime.h>
#include <hip/hip_fp16.h>

constexpr int P  = 128;  // input features
constexpr int H  = 64;   // hidden 1
constexpr int H2 = 128;  // hidden 2
constexpr int C  = 2;    // classes

constexpr int BW_LOG = 7;        // bucket width = 128 destinations
constexpr int BWID   = 128;
constexpr int NBMAX  = 512;      // max buckets supported (n <= 65536)
constexpr int T1     = 8192;     // edges per partition block
constexpr int CAP2   = 15360;    // k_csr LDS staging capacity (ints)

__device__ __forceinline__ unsigned packh2(float a, float b){
  unsigned short la = __half_as_ushort(__float2half_rn(a));
  unsigned short lb = __half_as_ushort(__float2half_rn(b));
  return (unsigned)la | ((unsigned)lb << 16);
}

// ---------------- CSR build (two-level LDS-staged partition) ----------------
__global__ void k_zero(int* __restrict__ p, int n){
  int i = blockIdx.x*blockDim.x + threadIdx.x;
  if(i<n) p[i]=0;
}

__global__ __launch_bounds__(256) void k_bhist(const int* __restrict__ col,
                                               int* __restrict__ bcnt, int e, int nb){
  __shared__ int h[NBMAX];
  for(int i=threadIdx.x;i<nb;i+=256) h[i]=0;
  __syncthreads();
  int b0 = blockIdx.x*2048;
  #pragma unroll
  for(int u=0;u<8;u++){
    int idx = b0 + u*256 + threadIdx.x;
    if(idx<e) atomicAdd(&h[col[idx]>>BW_LOG], 1);
  }
  __syncthreads();
  for(int i=threadIdx.x;i<nb;i+=256) if(h[i]) atomicAdd(&bcnt[i], h[i]);
}

__global__ __launch_bounds__(NBMAX) void k_bscan(const int* __restrict__ bcnt,
                                                 int* __restrict__ bstart,
                                                 int* __restrict__ bcursor, int nb){
  __shared__ int sm[NBMAX];
  int t = threadIdx.x;
  int v = (t<nb)? bcnt[t] : 0;
  sm[t]=v; __syncthreads();
  for(int d=1; d<NBMAX; d<<=1){
    int u = (t>=d)? sm[t-d] : 0;
    __syncthreads();
    sm[t]+=u;
    __syncthreads();
  }
  if(t<nb){ int s = sm[t]-v; bstart[t]=s; bcursor[t]=s; }
}

__global__ __launch_bounds__(1024) void k_part(const int* __restrict__ row,
                                               const int* __restrict__ col,
                                               int* __restrict__ bcursor,
                                               unsigned* __restrict__ pairs, int e, int nb){
  __shared__ unsigned stage[T1];
  __shared__ int hist[NBMAX];
  __shared__ int base[NBMAX];
  __shared__ int gpos[NBMAX];
  int tid = threadIdx.x;
  int e0 = blockIdx.x*T1;
  int cnt = min(T1, e-e0);
  for(int i=tid;i<nb;i+=1024) hist[i]=0;
  __syncthreads();
  int myb[8]; int myrank[8]; unsigned mypack[8];
  #pragma unroll
  for(int u=0;u<8;u++){
    int idx = u*1024 + tid;
    if(idx<cnt){
      int c = col[e0+idx], r = row[e0+idx];
      int b = c>>BW_LOG;
      myb[u] = b;
      mypack[u] = ((unsigned)r<<BW_LOG) | (unsigned)(c & (BWID-1));
      myrank[u] = atomicAdd(&hist[b], 1);
    } else myb[u] = -1;
  }
  __syncthreads();
  if(tid<NBMAX) base[tid] = (tid<nb)? hist[tid] : 0;
  __syncthreads();
  for(int d=1; d<NBMAX; d<<=1){
    int u2 = 0;
    if(tid<NBMAX && tid>=d) u2 = base[tid-d];
    __syncthreads();
    if(tid<NBMAX) base[tid] += u2;
    __syncthreads();
  }
  if(tid<nb){
    int ex = base[tid] - hist[tid];
    base[tid] = ex;
    gpos[tid] = atomicAdd(&bcursor[tid], hist[tid]);
  }
  __syncthreads();
  #pragma unroll
  for(int u=0;u<8;u++){
    if(myb[u]>=0) stage[ base[myb[u]] + myrank[u] ] = mypack[u];
  }
  __syncthreads();
  int wave = tid>>6, lane = tid&63;
  for(int b=wave; b<nb; b+=16){
    int len = hist[b], lo = base[b], go = gpos[b];
    for(int k=lane; k<len; k+=64) pairs[go+k] = stage[lo+k];
  }
}

__global__ __launch_bounds__(256) void k_csr(const unsigned* __restrict__ pairs,
                                             const int* __restrict__ bstart,
                                             const int* __restrict__ bcnt,
                                             int* __restrict__ srcA,
                                             int* __restrict__ rowptr,
                                             float* __restrict__ dinv,
                                             int n, int e){
  __shared__ int hist[BWID];
  __shared__ int base[BWID];
  __shared__ int cur[BWID];
  __shared__ int stageS[CAP2];
  int b = blockIdx.x, tid = threadIdx.x;
  int lo = bstart[b], cnt = bcnt[b];
  if(tid<BWID) hist[tid]=0;
  __syncthreads();
  for(int i=tid;i<cnt;i+=256) atomicAdd(&hist[pairs[lo+i] & (BWID-1)], 1);
  __syncthreads();
  if(tid<BWID) base[tid] = hist[tid];
  __syncthreads();
  for(int d=1; d<BWID; d<<=1){
    int u = 0;
    if(tid<BWID && tid>=d) u = base[tid-d];
    __syncthreads();
    if(tid<BWID) base[tid] += u;
    __syncthreads();
  }
  if(tid<BWID){
    int ex = base[tid] - hist[tid];
    base[tid] = ex;
    cur[tid] = ex;
    int node = (b<<BW_LOG) + tid;
    if(node<n){
      rowptr[node] = lo + ex;
      dinv[node]   = rsqrtf((float)hist[tid] + 1.0f);
    }
  }
  if(b==0 && tid==0) rowptr[n] = e;
  __syncthreads();
  if(cnt<=CAP2){
    for(int i=tid;i<cnt;i+=256){
      unsigned p = pairs[lo+i];
      int pos = atomicAdd(&cur[p & (BWID-1)], 1);
      stageS[pos] = (int)(p>>BW_LOG);
    }
    __syncthreads();
    for(int i=tid;i<cnt;i+=256) srcA[lo+i] = stageS[i];
  } else {
    for(int i=tid;i<cnt;i+=256){
      unsigned p = pairs[lo+i];
      int pos = atomicAdd(&cur[p & (BWID-1)], 1);
      srcA[lo+pos] = (int)(p>>BW_LOG);
    }
  }
}

// ---------------- GEMM1: tiled 64x64 -> fp16 chunk-major out [2][n][32] ----------------
__global__ __launch_bounds__(256) void k_gemm1(const float* __restrict__ x,
                                               const float* __restrict__ W,
                                               const float* __restrict__ dinv,
                                               unsigned* __restrict__ out, int n){
  __shared__ float xs[64][68];
  __shared__ float ws[64][64];
  int tid = threadIdx.x;
  int tx = tid & 15, ty = tid >> 4;
  int r0 = blockIdx.x*64;
  float acc[4][4] = {};
  const float4* x4 = (const float4*)x;
  const float4* W4 = (const float4*)W;
  for(int kh=0; kh<2; ++kh){
    __syncthreads();
    #pragma unroll
    for(int it=0; it<4; ++it){
      int idx = tid + 256*it;
      int r = idx >> 4, k4 = idx & 15;
      int gr = r0 + r;
      float4 v = (gr<n) ? x4[(size_t)gr*32 + kh*16 + k4] : make_float4(0.f,0.f,0.f,0.f);
      *(float4*)&xs[r][4*k4] = v;
    }
    #pragma unroll
    for(int it=0; it<4; ++it){
      int idx = tid + 256*it;
      int kk = idx >> 4, c4 = idx & 15;
      *(float4*)&ws[kk][4*c4] = W4[(size_t)(kh*64+kk)*16 + c4];
    }
    __syncthreads();
    #pragma unroll 8
    for(int kk=0; kk<64; ++kk){
      float xv0 = xs[4*ty+0][kk];
      float xv1 = xs[4*ty+1][kk];
      float xv2 = xs[4*ty+2][kk];
      float xv3 = xs[4*ty+3][kk];
      float4 wv = *(const float4*)&ws[kk][4*tx];
      acc[0][0] += xv0*wv.x; acc[0][1] += xv0*wv.y; acc[0][2] += xv0*wv.z; acc[0][3] += xv0*wv.w;
      acc[1][0] += xv1*wv.x; acc[1][1] += xv1*wv.y; acc[1][2] += xv1*wv.z; acc[1][3] += xv1*wv.w;
      acc[2][0] += xv2*wv.x; acc[2][1] += xv2*wv.y; acc[2][2] += xv2*wv.z; acc[2][3] += xv2*wv.w;
      acc[3][0] += xv3*wv.x; acc[3][1] += xv3*wv.y; acc[3][2] += xv3*wv.z; acc[3][3] += xv3*wv.w;
    }
  }
  // fp16 chunk-major write: cols 4tx..4tx+3 -> chunk tx>>3, row = 16 uints
  unsigned* ob = out + (size_t)(tx>>3)*n*16 + 2*(tx&7);
  #pragma unroll
  for(int i=0;i<4;i++){
    int gr = r0 + 4*ty + i;
    if(gr<n){
      float d = dinv[gr];
      uint2 w;
      w.x = packh2(acc[i][0]*d, acc[i][1]*d);
      w.y = packh2(acc[i][2]*d, acc[i][3]*d);
      *(uint2*)&ob[(size_t)gr*16] = w;
    }
  }
}

// ---------------- GEMM2+GEMM3 fused (a2 row-major f32 [n][64]) ----------------
__global__ __launch_bounds__(256) void k_gemm23(const float* __restrict__ a2,
                                                const float* __restrict__ W2,
                                                const float* __restrict__ b2,
                                                const float* __restrict__ W3,
                                                const float* __restrict__ dinv,
                                                float* __restrict__ u3, int n){
  __shared__ float as[64][68];
  __shared__ float ws[64][128];
  __shared__ float w3s[H2*C];
  __shared__ float b2s[H2];
  int tid = threadIdx.x;
  int tx = tid & 15, ty = tid >> 4;
  int r0 = blockIdx.x*64;
  const float4* a4 = (const float4*)a2;
  const float4* W24 = (const float4*)W2;
  #pragma unroll
  for(int it=0; it<4; ++it){
    int idx = tid + 256*it;
    int r = idx >> 4, k4 = idx & 15;
    int gr = r0 + r;
    float4 v = (gr<n) ? a4[(size_t)gr*16 + k4] : make_float4(0.f,0.f,0.f,0.f);
    *(float4*)&as[r][4*k4] = v;
  }
  #pragma unroll
  for(int it=0; it<8; ++it){
    int idx = tid + 256*it;
    int kk = idx >> 5, c4 = idx & 31;
    *(float4*)&ws[kk][4*c4] = W24[(size_t)kk*32 + c4];
  }
  if(tid < H2*C) w3s[tid] = W3[tid];
  if(tid < H2)   b2s[tid] = b2[tid];
  __syncthreads();
  float acc[4][8] = {};
  #pragma unroll 4
  for(int kk=0; kk<64; ++kk){
    float xv0 = as[4*ty+0][kk];
    float xv1 = as[4*ty+1][kk];
    float xv2 = as[4*ty+2][kk];
    float xv3 = as[4*ty+3][kk];
    float4 wa = *(const float4*)&ws[kk][8*tx];
    float4 wb = *(const float4*)&ws[kk][8*tx+4];
    acc[0][0]+=xv0*wa.x; acc[0][1]+=xv0*wa.y; acc[0][2]+=xv0*wa.z; acc[0][3]+=xv0*wa.w;
    acc[0][4]+=xv0*wb.x; acc[0][5]+=xv0*wb.y; acc[0][6]+=xv0*wb.z; acc[0][7]+=xv0*wb.w;
    acc[1][0]+=xv1*wa.x; acc[1][1]+=xv1*wa.y; acc[1][2]+=xv1*wa.z; acc[1][3]+=xv1*wa.w;
    acc[1][4]+=xv1*wb.x; acc[1][5]+=xv1*wb.y; acc[1][6]+=xv1*wb.z; acc[1][7]+=xv1*wb.w;
    acc[2][0]+=xv2*wa.x; acc[2][1]+=xv2*wa.y; acc[2][2]+=xv2*wa.z; acc[2][3]+=xv2*wa.w;
    acc[2][4]+=xv2*wb.x; acc[2][5]+=xv2*wb.y; acc[2][6]+=xv2*wb.z; acc[2][7]+=xv2*wb.w;
    acc[3][0]+=xv3*wa.x; acc[3][1]+=xv3*wa.y; acc[3][2]+=xv3*wa.z; acc[3][3]+=xv3*wa.w;
    acc[3][4]+=xv3*wb.x; acc[3][5]+=xv3*wb.y; acc[3][6]+=xv3*wb.z; acc[3][7]+=xv3*wb.w;
  }
  float p[4][2] = {};
  #pragma unroll
  for(int j=0;j<8;j++){
    int c = 8*tx + j;
    float w30 = w3s[2*c], w31 = w3s[2*c+1], bb = b2s[c];
    #pragma unroll
    for(int i=0;i<4;i++){
      float g = fmaxf(acc[i][j] + bb, 0.f);
      p[i][0] += g*w30;
      p[i][1] += g*w31;
    }
  }
  #pragma unroll
  for(int d=1; d<16; d<<=1){
    #pragma unroll
    for(int i=0;i<4;i++){
      p[i][0] += __shfl_xor(p[i][0], d);
      p[i][1] += __shfl_xor(p[i][1], d);
    }
  }
  if(tx==0){
    #pragma unroll
    for(int i=0;i<4;i++){
      int gr = r0 + 4*ty + i;
      if(gr<n){
        float d = dinv[gr];
        u3[2*gr]   = d*p[i][0];
        u3[2*gr+1] = d*p[i][1];
      }
    }
  }
}

// ---------------- fp16 chunked pull: packed v_pk_add_f16 accumulation ----------------
// table: fp16 chunk-major [2][n][32] (row = 64B). 16 edge-slots x 4 lanes x 16B.
// Per-lane fp16 accumulation chain ~deg/16 edges (short -> safe); f32 reduce/epilogue.
// MODE 1: g1s(fp16 cm) = dinv*relu(dinv*sum + bias)   MODE 2: a2(f32 rm) = dinv*sum
template<int MODE>
__global__ __launch_bounds__(256) void k_pullh(const int* __restrict__ src,
                                               const int* __restrict__ rowptr,
                                               const uint4* __restrict__ th,
                                               const float* __restrict__ dinv,
                                               const float* __restrict__ bias,
                                               void* __restrict__ outp, int n){
  int chunk = blockIdx.x & 1;
  int node  = (blockIdx.x >> 1)*4 + (threadIdx.x>>6);
  if(node>=n) return;
  int lane = threadIdx.x & 63;
  int slot = lane >> 2;     // edge slot 0..15
  int q    = lane & 3;      // 16B quad within 64B row
  const uint4* t4 = th + (size_t)chunk*n*4;
  __half2 h0 = __float2half2_rn(0.f), h1 = h0, h2v = h0, h3 = h0;
  __half2 g0 = h0, g1 = h0, g2v = h0, g3 = h0;
  int beg = rowptr[node], end = rowptr[node+1];
  int j = beg;
  for(; j+32<=end; j+=32){
    int s0 = src[j+slot], s1 = src[j+16+slot];
    uint4 r0 = t4[(size_t)s0*4+q];
    uint4 r1 = t4[(size_t)s1*4+q];
    const __half2* p0 = (const __half2*)&r0;
    const __half2* p1 = (const __half2*)&r1;
    h0 = __hadd2(h0, p0[0]); h1 = __hadd2(h1, p0[1]);
    h2v= __hadd2(h2v,p0[2]); h3 = __hadd2(h3, p0[3]);
    g0 = __hadd2(g0, p1[0]); g1 = __hadd2(g1, p1[1]);
    g2v= __hadd2(g2v,p1[2]); g3 = __hadd2(g3, p1[3]);
  }
  for(; j+16<=end; j+=16){
    int s = src[j+slot];
    uint4 r = t4[(size_t)s*4+q];
    const __half2* p = (const __half2*)&r;
    h0 = __hadd2(h0, p[0]); h1 = __hadd2(h1, p[1]);
    h2v= __hadd2(h2v,p[2]); h3 = __hadd2(h3, p[3]);
  }
  if(j+slot < end){
    int s = src[j+slot];
    uint4 r = t4[(size_t)s*4+q];
    const __half2* p = (const __half2*)&r;
    g0 = __hadd2(g0, p[0]); g1 = __hadd2(g1, p[1]);
    g2v= __hadd2(g2v,p[2]); g3 = __hadd2(g3, p[3]);
  }
  // convert to f32 (combine the two fp16 accumulator banks in f32)
  float a[8];
  {
    float2 fa, fb;
    fa = __half22float2(h0); fb = __half22float2(g0); a[0]=fa.x+fb.x; a[1]=fa.y+fb.y;
    fa = __half22float2(h1); fb = __half22float2(g1); a[2]=fa.x+fb.x; a[3]=fa.y+fb.y;
    fa = __half22float2(h2v);fb = __half22float2(g2v);a[4]=fa.x+fb.x; a[5]=fa.y+fb.y;
    fa = __half22float2(h3); fb = __half22float2(g3); a[6]=fa.x+fb.x; a[7]=fa.y+fb.y;
  }
  // reduce over slot bits (lane bits 2..5) in f32
  #pragma unroll
  for(int d=4; d<64; d<<=1){
    #pragma unroll
    for(int i=0;i<8;i++) a[i] += __shfl_xor(a[i], d);
  }
  if(slot==0){
    uint4 sr = t4[(size_t)node*4+q];   // self-loop row
    const __half2* p = (const __half2*)&sr;
    float2 f0 = __half22float2(p[0]), f1 = __half22float2(p[1]);
    float2 f2 = __half22float2(p[2]), f3 = __half22float2(p[3]);
    a[0]+=f0.x; a[1]+=f0.y; a[2]+=f1.x; a[3]+=f1.y;
    a[4]+=f2.x; a[5]+=f2.y; a[6]+=f3.x; a[7]+=f3.y;
    float dv = dinv[node];
    if(MODE==1){
      const float* bq = bias + chunk*32 + 8*q;
      float o[8];
      #pragma unroll
      for(int i=0;i<8;i++) o[i] = dv * fmaxf(dv*a[i] + bq[i], 0.f);
      uint4 w;
      w.x = packh2(o[0],o[1]); w.y = packh2(o[2],o[3]);
      w.z = packh2(o[4],o[5]); w.w = packh2(o[6],o[7]);
      ((uint4*)outp)[(size_t)chunk*n*4 + (size_t)node*4 + q] = w;
    } else {
      float* orow = (float*)outp + (size_t)node*64 + chunk*32 + 8*q;
      *(float4*)orow     = make_float4(dv*a[0], dv*a[1], dv*a[2], dv*a[3]);
      *(float4*)(orow+4) = make_float4(dv*a[4], dv*a[5], dv*a[6], dv*a[7]);
    }
  }
}

// F=2 pull + bias + log_softmax fused
__global__ __launch_bounds__(256) void k_pull2_lsm(const int* __restrict__ src,
                                                   const int* __restrict__ rowptr,
                                                   const float* __restrict__ u3,
                                                   const float* __restrict__ dinv,
                                                   const float* __restrict__ b3,
                                                   float* __restrict__ out, int n){
  int node = blockIdx.x*4 + (threadIdx.x>>6);
  int lane = threadIdx.x & 63;
  if(node>=n) return;
  const float2* u = (const float2*)u3;
  int beg = rowptr[node], end = rowptr[node+1];
  float p0=0.f, p1=0.f, q0=0.f, q1=0.f;
  int j = beg + lane;
  for(; j+64 < end; j += 128){
    float2 A = u[src[j]];
    float2 B = u[src[j+64]];
    p0 += A.x; p1 += A.y; q0 += B.x; q1 += B.y;
  }
  if(j < end){ float2 A = u[src[j]]; p0 += A.x; p1 += A.y; }
  p0 += q0; p1 += q1;
  #pragma unroll
  for(int d=32; d; d>>=1){ p0 += __shfl_xor(p0,d); p1 += __shfl_xor(p1,d); }
  if(lane==0){
    float d = dinv[node];
    float2 self = u[node];
    float z0 = d*(p0 + self.x) + b3[0];
    float z1 = d*(p1 + self.y) + b3[1];
    float m = fmaxf(z0,z1);
    float l = m + logf(expf(z0-m)+expf(z1-m));
    out[2*node]   = z0-l;
    out[2*node+1] = z1-l;
  }
}

extern "C" void kernel_launch(void* const* d_in, const int* in_sizes, int n_in,
                              void* d_out, int out_size, void* d_ws, size_t ws_size,
                              hipStream_t stream){
  const float* x  = (const float*)d_in[0];
  const int*   ei = (const int*)  d_in[1];
  const float* W1 = (const float*)d_in[2];
  const float* b1 = (const float*)d_in[3];
  const float* W2 = (const float*)d_in[4];
  const float* b2 = (const float*)d_in[5];
  const float* W3 = (const float*)d_in[6];
  const float* b3 = (const float*)d_in[7];
  float* out = (float*)d_out;

  const int n = in_sizes[0] / P;       // 50000
  const int e = in_sizes[1] / 2;       // 1600000
  const int* row = ei;
  const int* col = ei + e;
  const int nb = (n + BWID - 1) >> BW_LOG;

  float* ws   = (float*)d_ws;
  size_t off = 0;
  float* dinv = ws + off; off += n;
  float* R1   = ws + off; off += (size_t)64*n;
  float* R2   = ws + off; off += (size_t)128*n;
  int* rowptr = (int*)(ws + off); off += n+1;
  int* srcA   = (int*)(ws + off); off += e;
  int* bcnt   = (int*)(ws + off); off += NBMAX;
  int* bstart = (int*)(ws + off); off += NBMAX;
  int* bcursor= (int*)(ws + off); off += NBMAX;

  unsigned* pairs = (unsigned*)R2;           // live only during CSR build

  unsigned* u1h = (unsigned*)R1;             // fp16 cm [2][n][32] (dead after pull-1)
  unsigned* g1h = (unsigned*)R2;             // fp16 cm [2][n][32] (dead after pull-2)
  float*    a2  = R2 + (size_t)32*n;         // f32 rm [n][64]     (dead after gemm23)
  float*    u3  = R1;                        // f32 [n][2]         (dead after pull2_lsm)

  const int BT = 256;

  k_zero <<<(nb+BT-1)/BT, BT, 0, stream>>>(bcnt, nb);
  k_bhist<<<(e+2047)/2048, BT, 0, stream>>>(col, bcnt, e, nb);
  k_bscan<<<1, NBMAX, 0, stream>>>(bcnt, bstart, bcursor, nb);
  k_part <<<(e+T1-1)/T1, 1024, 0, stream>>>(row, col, bcursor, pairs, e, nb);
  k_csr  <<<nb, BT, 0, stream>>>(pairs, bstart, bcnt, srcA, rowptr, dinv, n, e);

  k_gemm1<<<(n+63)/64, BT, 0, stream>>>(x, W1, dinv, u1h, n);

  const int pg = ((n+3)/4)*2;   // (node-block, chunk) pairs; chunk = bid&1
  k_pullh<1><<<pg, BT, 0, stream>>>(srcA, rowptr, (const uint4*)u1h, dinv, b1, (void*)g1h, n);
  k_pullh<2><<<pg, BT, 0, stream>>>(srcA, rowptr, (const uint4*)g1h, dinv, nullptr, (void*)a2, n);

  k_gemm23<<<(n+63)/64, BT, 0, stream>>>(a2, W2, b2, W3, dinv, u3, n);
  k_pull2_lsm<<<(n+3)/4, BT, 0, stream>>>(srcA, rowptr, u3, dinv, b3, out, n);
}

// Round 11
// 180.260 us; speedup vs baseline: 1.0962x; 1.0962x over previous
//
#include <hip/hip_runtime.h>
#include <hip/hip_fp16.h>

constexpr int P  = 128;  // input features
constexpr int H  = 64;   // hidden 1
constexpr int H2 = 128;  // hidden 2
constexpr int C  = 2;    // classes

constexpr int BW_LOG = 7;        // bucket width = 128 destinations
constexpr int BWID   = 128;
constexpr int NBMAX  = 512;      // max buckets supported (n <= 65536)
constexpr int T1     = 8192;     // edges per partition block
constexpr int CAP2   = 15360;    // k_csr LDS staging capacity (ints)

__device__ __forceinline__ unsigned packh2(float a, float b){
  unsigned short la = __half_as_ushort(__float2half_rn(a));
  unsigned short lb = __half_as_ushort(__float2half_rn(b));
  return (unsigned)la | ((unsigned)lb << 16);
}

// ---------------- CSR build (two-level LDS-staged partition) ----------------
__global__ void k_zero(int* __restrict__ p, int n){
  int i = blockIdx.x*blockDim.x + threadIdx.x;
  if(i<n) p[i]=0;
}

__global__ __launch_bounds__(256) void k_bhist(const int* __restrict__ col,
                                               int* __restrict__ bcnt, int e, int nb){
  __shared__ int h[NBMAX];
  for(int i=threadIdx.x;i<nb;i+=256) h[i]=0;
  __syncthreads();
  int b0 = blockIdx.x*2048;
  #pragma unroll
  for(int u=0;u<8;u++){
    int idx = b0 + u*256 + threadIdx.x;
    if(idx<e) atomicAdd(&h[col[idx]>>BW_LOG], 1);
  }
  __syncthreads();
  for(int i=threadIdx.x;i<nb;i+=256) if(h[i]) atomicAdd(&bcnt[i], h[i]);
}

__global__ __launch_bounds__(NBMAX) void k_bscan(const int* __restrict__ bcnt,
                                                 int* __restrict__ bstart,
                                                 int* __restrict__ bcursor, int nb){
  __shared__ int sm[NBMAX];
  int t = threadIdx.x;
  int v = (t<nb)? bcnt[t] : 0;
  sm[t]=v; __syncthreads();
  for(int d=1; d<NBMAX; d<<=1){
    int u = (t>=d)? sm[t-d] : 0;
    __syncthreads();
    sm[t]+=u;
    __syncthreads();
  }
  if(t<nb){ int s = sm[t]-v; bstart[t]=s; bcursor[t]=s; }
}

__global__ __launch_bounds__(1024) void k_part(const int* __restrict__ row,
                                               const int* __restrict__ col,
                                               int* __restrict__ bcursor,
                                               unsigned* __restrict__ pairs, int e, int nb){
  __shared__ unsigned stage[T1];
  __shared__ int hist[NBMAX];
  __shared__ int base[NBMAX];
  __shared__ int gpos[NBMAX];
  int tid = threadIdx.x;
  int e0 = blockIdx.x*T1;
  int cnt = min(T1, e-e0);
  for(int i=tid;i<nb;i+=1024) hist[i]=0;
  __syncthreads();
  int myb[8]; int myrank[8]; unsigned mypack[8];
  #pragma unroll
  for(int u=0;u<8;u++){
    int idx = u*1024 + tid;
    if(idx<cnt){
      int c = col[e0+idx], r = row[e0+idx];
      int b = c>>BW_LOG;
      myb[u] = b;
      mypack[u] = ((unsigned)r<<BW_LOG) | (unsigned)(c & (BWID-1));
      myrank[u] = atomicAdd(&hist[b], 1);
    } else myb[u] = -1;
  }
  __syncthreads();
  if(tid<NBMAX) base[tid] = (tid<nb)? hist[tid] : 0;
  __syncthreads();
  for(int d=1; d<NBMAX; d<<=1){
    int u2 = 0;
    if(tid<NBMAX && tid>=d) u2 = base[tid-d];
    __syncthreads();
    if(tid<NBMAX) base[tid] += u2;
    __syncthreads();
  }
  if(tid<nb){
    int ex = base[tid] - hist[tid];
    base[tid] = ex;
    gpos[tid] = atomicAdd(&bcursor[tid], hist[tid]);
  }
  __syncthreads();
  #pragma unroll
  for(int u=0;u<8;u++){
    if(myb[u]>=0) stage[ base[myb[u]] + myrank[u] ] = mypack[u];
  }
  __syncthreads();
  int wave = tid>>6, lane = tid&63;
  for(int b=wave; b<nb; b+=16){
    int len = hist[b], lo = base[b], go = gpos[b];
    for(int k=lane; k<len; k+=64) pairs[go+k] = stage[lo+k];
  }
}

// stores srcA as BYTE offsets into the fp16 table: src_node*128 = pair & ~0x7F
__global__ __launch_bounds__(256) void k_csr(const unsigned* __restrict__ pairs,
                                             const int* __restrict__ bstart,
                                             const int* __restrict__ bcnt,
                                             unsigned* __restrict__ srcA,
                                             int* __restrict__ rowptr,
                                             float* __restrict__ dinv,
                                             int n, int e){
  __shared__ int hist[BWID];
  __shared__ int base[BWID];
  __shared__ int cur[BWID];
  __shared__ unsigned stageS[CAP2];
  int b = blockIdx.x, tid = threadIdx.x;
  int lo = bstart[b], cnt = bcnt[b];
  if(tid<BWID) hist[tid]=0;
  __syncthreads();
  for(int i=tid;i<cnt;i+=256) atomicAdd(&hist[pairs[lo+i] & (BWID-1)], 1);
  __syncthreads();
  if(tid<BWID) base[tid] = hist[tid];
  __syncthreads();
  for(int d=1; d<BWID; d<<=1){
    int u = 0;
    if(tid<BWID && tid>=d) u = base[tid-d];
    __syncthreads();
    if(tid<BWID) base[tid] += u;
    __syncthreads();
  }
  if(tid<BWID){
    int ex = base[tid] - hist[tid];
    base[tid] = ex;
    cur[tid] = ex;
    int node = (b<<BW_LOG) + tid;
    if(node<n){
      rowptr[node] = lo + ex;
      dinv[node]   = rsqrtf((float)hist[tid] + 1.0f);
    }
  }
  if(b==0 && tid==0) rowptr[n] = e;
  __syncthreads();
  if(cnt<=CAP2){
    for(int i=tid;i<cnt;i+=256){
      unsigned p = pairs[lo+i];
      int pos = atomicAdd(&cur[p & (BWID-1)], 1);
      stageS[pos] = p & ~0x7Fu;     // src_node*128 (byte offset)
    }
    __syncthreads();
    for(int i=tid;i<cnt;i+=256) srcA[lo+i] = stageS[i];
  } else {
    for(int i=tid;i<cnt;i+=256){
      unsigned p = pairs[lo+i];
      int pos = atomicAdd(&cur[p & (BWID-1)], 1);
      srcA[lo+pos] = p & ~0x7Fu;
    }
  }
}

// ---------------- GEMM1: tiled 64x64 -> fp16 row-major out [n][64] ----------------
__global__ __launch_bounds__(256) void k_gemm1(const float* __restrict__ x,
                                               const float* __restrict__ W,
                                               const float* __restrict__ dinv,
                                               unsigned* __restrict__ out, int n){
  __shared__ float xs[64][68];
  __shared__ float ws[64][64];
  int tid = threadIdx.x;
  int tx = tid & 15, ty = tid >> 4;
  int r0 = blockIdx.x*64;
  float acc[4][4] = {};
  const float4* x4 = (const float4*)x;
  const float4* W4 = (const float4*)W;
  for(int kh=0; kh<2; ++kh){
    __syncthreads();
    #pragma unroll
    for(int it=0; it<4; ++it){
      int idx = tid + 256*it;
      int r = idx >> 4, k4 = idx & 15;
      int gr = r0 + r;
      float4 v = (gr<n) ? x4[(size_t)gr*32 + kh*16 + k4] : make_float4(0.f,0.f,0.f,0.f);
      *(float4*)&xs[r][4*k4] = v;
    }
    #pragma unroll
    for(int it=0; it<4; ++it){
      int idx = tid + 256*it;
      int kk = idx >> 4, c4 = idx & 15;
      *(float4*)&ws[kk][4*c4] = W4[(size_t)(kh*64+kk)*16 + c4];
    }
    __syncthreads();
    #pragma unroll 8
    for(int kk=0; kk<64; ++kk){
      float xv0 = xs[4*ty+0][kk];
      float xv1 = xs[4*ty+1][kk];
      float xv2 = xs[4*ty+2][kk];
      float xv3 = xs[4*ty+3][kk];
      float4 wv = *(const float4*)&ws[kk][4*tx];
      acc[0][0] += xv0*wv.x; acc[0][1] += xv0*wv.y; acc[0][2] += xv0*wv.z; acc[0][3] += xv0*wv.w;
      acc[1][0] += xv1*wv.x; acc[1][1] += xv1*wv.y; acc[1][2] += xv1*wv.z; acc[1][3] += xv1*wv.w;
      acc[2][0] += xv2*wv.x; acc[2][1] += xv2*wv.y; acc[2][2] += xv2*wv.z; acc[2][3] += xv2*wv.w;
      acc[3][0] += xv3*wv.x; acc[3][1] += xv3*wv.y; acc[3][2] += xv3*wv.z; acc[3][3] += xv3*wv.w;
    }
  }
  // fp16 row-major write: row = 32 uints (64 halves); thread tx owns cols 4tx..4tx+3
  #pragma unroll
  for(int i=0;i<4;i++){
    int gr = r0 + 4*ty + i;
    if(gr<n){
      float d = dinv[gr];
      uint2 w;
      w.x = packh2(acc[i][0]*d, acc[i][1]*d);
      w.y = packh2(acc[i][2]*d, acc[i][3]*d);
      *(uint2*)&out[(size_t)gr*32 + 2*tx] = w;
    }
  }
}

// ---------------- GEMM2+GEMM3 fused (a2 row-major f32 [n][64]) ----------------
__global__ __launch_bounds__(256) void k_gemm23(const float* __restrict__ a2,
                                                const float* __restrict__ W2,
                                                const float* __restrict__ b2,
                                                const float* __restrict__ W3,
                                                const float* __restrict__ dinv,
                                                float* __restrict__ u3, int n){
  __shared__ float as[64][68];
  __shared__ float ws[64][128];
  __shared__ float w3s[H2*C];
  __shared__ float b2s[H2];
  int tid = threadIdx.x;
  int tx = tid & 15, ty = tid >> 4;
  int r0 = blockIdx.x*64;
  const float4* a4 = (const float4*)a2;
  const float4* W24 = (const float4*)W2;
  #pragma unroll
  for(int it=0; it<4; ++it){
    int idx = tid + 256*it;
    int r = idx >> 4, k4 = idx & 15;
    int gr = r0 + r;
    float4 v = (gr<n) ? a4[(size_t)gr*16 + k4] : make_float4(0.f,0.f,0.f,0.f);
    *(float4*)&as[r][4*k4] = v;
  }
  #pragma unroll
  for(int it=0; it<8; ++it){
    int idx = tid + 256*it;
    int kk = idx >> 5, c4 = idx & 31;
    *(float4*)&ws[kk][4*c4] = W24[(size_t)kk*32 + c4];
  }
  if(tid < H2*C) w3s[tid] = W3[tid];
  if(tid < H2)   b2s[tid] = b2[tid];
  __syncthreads();
  float acc[4][8] = {};
  #pragma unroll 4
  for(int kk=0; kk<64; ++kk){
    float xv0 = as[4*ty+0][kk];
    float xv1 = as[4*ty+1][kk];
    float xv2 = as[4*ty+2][kk];
    float xv3 = as[4*ty+3][kk];
    float4 wa = *(const float4*)&ws[kk][8*tx];
    float4 wb = *(const float4*)&ws[kk][8*tx+4];
    acc[0][0]+=xv0*wa.x; acc[0][1]+=xv0*wa.y; acc[0][2]+=xv0*wa.z; acc[0][3]+=xv0*wa.w;
    acc[0][4]+=xv0*wb.x; acc[0][5]+=xv0*wb.y; acc[0][6]+=xv0*wb.z; acc[0][7]+=xv0*wb.w;
    acc[1][0]+=xv1*wa.x; acc[1][1]+=xv1*wa.y; acc[1][2]+=xv1*wa.z; acc[1][3]+=xv1*wa.w;
    acc[1][4]+=xv1*wb.x; acc[1][5]+=xv1*wb.y; acc[1][6]+=xv1*wb.z; acc[1][7]+=xv1*wb.w;
    acc[2][0]+=xv2*wa.x; acc[2][1]+=xv2*wa.y; acc[2][2]+=xv2*wa.z; acc[2][3]+=xv2*wa.w;
    acc[2][4]+=xv2*wb.x; acc[2][5]+=xv2*wb.y; acc[2][6]+=xv2*wb.z; acc[2][7]+=xv2*wb.w;
    acc[3][0]+=xv3*wa.x; acc[3][1]+=xv3*wa.y; acc[3][2]+=xv3*wa.z; acc[3][3]+=xv3*wa.w;
    acc[3][4]+=xv3*wb.x; acc[3][5]+=xv3*wb.y; acc[3][6]+=xv3*wb.z; acc[3][7]+=xv3*wb.w;
  }
  float p[4][2] = {};
  #pragma unroll
  for(int j=0;j<8;j++){
    int c = 8*tx + j;
    float w30 = w3s[2*c], w31 = w3s[2*c+1], bb = b2s[c];
    #pragma unroll
    for(int i=0;i<4;i++){
      float g = fmaxf(acc[i][j] + bb, 0.f);
      p[i][0] += g*w30;
      p[i][1] += g*w31;
    }
  }
  #pragma unroll
  for(int d=1; d<16; d<<=1){
    #pragma unroll
    for(int i=0;i<4;i++){
      p[i][0] += __shfl_xor(p[i][0], d);
      p[i][1] += __shfl_xor(p[i][1], d);
    }
  }
  if(tx==0){
    #pragma unroll
    for(int i=0;i<4;i++){
      int gr = r0 + 4*ty + i;
      if(gr<n){
        float d = dinv[gr];
        u3[2*gr]   = d*p[i][0];
        u3[2*gr+1] = d*p[i][1];
      }
    }
  }
}

// ---------------- merged fp16 pull: wave per node, 8 edge-slots x 8 lanes x 16B ----------------
// table fp16 row-major [n][64] (128B rows). srcA = byte offsets (src*128).
// MODE 1: g1h(fp16 rm) = dinv*relu(dinv*sum + bias)   MODE 2: a2(f32 rm) = dinv*sum
template<int MODE>
__global__ __launch_bounds__(256) void k_pullh(const unsigned* __restrict__ src,
                                               const int* __restrict__ rowptr,
                                               const char* __restrict__ tb0,
                                               const float* __restrict__ dinv,
                                               const float* __restrict__ bias,
                                               void* __restrict__ outp, int n){
  int node = blockIdx.x*4 + (threadIdx.x>>6);
  if(node>=n) return;
  int lane = threadIdx.x & 63;
  int slot = lane >> 3;      // edge slot 0..7
  int q    = lane & 7;       // 16B quad within 128B row
  const char* tb = tb0 + q*16;   // per-lane base; gather addr = tb + srcByteOff
  __half2 h0 = __float2half2_rn(0.f), h1 = h0, h2v = h0, h3 = h0;
  __half2 g0 = h0, g1 = h0, g2v = h0, g3 = h0;
  int beg = rowptr[node], end = rowptr[node+1];
  int j = beg;
  for(; j+16<=end; j+=16){
    unsigned s0 = src[j+slot], s1 = src[j+8+slot];
    uint4 r0 = *(const uint4*)(tb + s0);
    uint4 r1 = *(const uint4*)(tb + s1);
    const __half2* p0 = (const __half2*)&r0;
    const __half2* p1 = (const __half2*)&r1;
    h0 = __hadd2(h0, p0[0]); h1 = __hadd2(h1, p0[1]);
    h2v= __hadd2(h2v,p0[2]); h3 = __hadd2(h3, p0[3]);
    g0 = __hadd2(g0, p1[0]); g1 = __hadd2(g1, p1[1]);
    g2v= __hadd2(g2v,p1[2]); g3 = __hadd2(g3, p1[3]);
  }
  for(; j+8<=end; j+=8){
    unsigned s = src[j+slot];
    uint4 r = *(const uint4*)(tb + s);
    const __half2* p = (const __half2*)&r;
    h0 = __hadd2(h0, p[0]); h1 = __hadd2(h1, p[1]);
    h2v= __hadd2(h2v,p[2]); h3 = __hadd2(h3, p[3]);
  }
  if(j+slot < end){
    unsigned s = src[j+slot];
    uint4 r = *(const uint4*)(tb + s);
    const __half2* p = (const __half2*)&r;
    g0 = __hadd2(g0, p[0]); g1 = __hadd2(g1, p[1]);
    g2v= __hadd2(g2v,p[2]); g3 = __hadd2(g3, p[3]);
  }
  // combine banks in f32
  float a[8];
  {
    float2 fa, fb;
    fa = __half22float2(h0); fb = __half22float2(g0); a[0]=fa.x+fb.x; a[1]=fa.y+fb.y;
    fa = __half22float2(h1); fb = __half22float2(g1); a[2]=fa.x+fb.x; a[3]=fa.y+fb.y;
    fa = __half22float2(h2v);fb = __half22float2(g2v);a[4]=fa.x+fb.x; a[5]=fa.y+fb.y;
    fa = __half22float2(h3); fb = __half22float2(g3); a[6]=fa.x+fb.x; a[7]=fa.y+fb.y;
  }
  // reduce over slot bits (lane bits 3..5)
  #pragma unroll
  for(int d=8; d<64; d<<=1){
    #pragma unroll
    for(int i=0;i<8;i++) a[i] += __shfl_xor(a[i], d);
  }
  if(slot==0){
    uint4 sr = *(const uint4*)(tb + (unsigned)node*128u);   // self-loop row
    const __half2* p = (const __half2*)&sr;
    float2 f0 = __half22float2(p[0]), f1 = __half22float2(p[1]);
    float2 f2 = __half22float2(p[2]), f3 = __half22float2(p[3]);
    a[0]+=f0.x; a[1]+=f0.y; a[2]+=f1.x; a[3]+=f1.y;
    a[4]+=f2.x; a[5]+=f2.y; a[6]+=f3.x; a[7]+=f3.y;
    float dv = dinv[node];
    if(MODE==1){
      const float* bq = bias + 8*q;   // lane q covers features 8q..8q+7
      float o[8];
      #pragma unroll
      for(int i=0;i<8;i++) o[i] = dv * fmaxf(dv*a[i] + bq[i], 0.f);
      uint4 w;
      w.x = packh2(o[0],o[1]); w.y = packh2(o[2],o[3]);
      w.z = packh2(o[4],o[5]); w.w = packh2(o[6],o[7]);
      ((uint4*)outp)[(size_t)node*8 + q] = w;
    } else {
      float* orow = (float*)outp + (size_t)node*64 + 8*q;
      *(float4*)orow     = make_float4(dv*a[0], dv*a[1], dv*a[2], dv*a[3]);
      *(float4*)(orow+4) = make_float4(dv*a[4], dv*a[5], dv*a[6], dv*a[7]);
    }
  }
}

// F=2 pull + bias + log_softmax fused; 4 nodes per wave (16 lanes each)
__global__ __launch_bounds__(256) void k_pull2_lsm(const unsigned* __restrict__ src,
                                                   const int* __restrict__ rowptr,
                                                   const float* __restrict__ u3,
                                                   const float* __restrict__ dinv,
                                                   const float* __restrict__ b3,
                                                   float* __restrict__ out, int n){
  int node = blockIdx.x*16 + (threadIdx.x>>4);
  int l16  = threadIdx.x & 15;
  if(node>=n) return;
  const char* ub = (const char*)u3;
  int beg = rowptr[node], end = rowptr[node+1];
  float p0=0.f, p1=0.f, q0=0.f, q1=0.f;
  int j = beg + l16;
  for(; j+16 < end; j += 32){
    float2 A = *(const float2*)(ub + (src[j]    >> 4));
    float2 B = *(const float2*)(ub + (src[j+16] >> 4));
    p0 += A.x; p1 += A.y; q0 += B.x; q1 += B.y;
  }
  if(j < end){
    float2 A = *(const float2*)(ub + (src[j] >> 4));
    p0 += A.x; p1 += A.y;
  }
  p0 += q0; p1 += q1;
  #pragma unroll
  for(int d=1; d<16; d<<=1){ p0 += __shfl_xor(p0,d); p1 += __shfl_xor(p1,d); }
  if(l16==0){
    float d = dinv[node];
    const float2 self = *(const float2*)(ub + (size_t)node*8);
    float z0 = d*(p0 + self.x) + b3[0];
    float z1 = d*(p1 + self.y) + b3[1];
    float m = fmaxf(z0,z1);
    float l = m + logf(expf(z0-m)+expf(z1-m));
    out[2*node]   = z0-l;
    out[2*node+1] = z1-l;
  }
}

extern "C" void kernel_launch(void* const* d_in, const int* in_sizes, int n_in,
                              void* d_out, int out_size, void* d_ws, size_t ws_size,
                              hipStream_t stream){
  const float* x  = (const float*)d_in[0];
  const int*   ei = (const int*)  d_in[1];
  const float* W1 = (const float*)d_in[2];
  const float* b1 = (const float*)d_in[3];
  const float* W2 = (const float*)d_in[4];
  const float* b2 = (const float*)d_in[5];
  const float* W3 = (const float*)d_in[6];
  const float* b3 = (const float*)d_in[7];
  float* out = (float*)d_out;

  const int n = in_sizes[0] / P;       // 50000
  const int e = in_sizes[1] / 2;       // 1600000
  const int* row = ei;
  const int* col = ei + e;
  const int nb = (n + BWID - 1) >> BW_LOG;

  float* ws   = (float*)d_ws;
  size_t off = 0;
  float* dinv = ws + off; off += n;
  float* R1   = ws + off; off += (size_t)64*n;
  float* R2   = ws + off; off += (size_t)128*n;
  int* rowptr = (int*)(ws + off); off += n+1;
  unsigned* srcA = (unsigned*)(ws + off); off += e;
  int* bcnt   = (int*)(ws + off); off += NBMAX;
  int* bstart = (int*)(ws + off); off += NBMAX;
  int* bcursor= (int*)(ws + off); off += NBMAX;

  unsigned* pairs = (unsigned*)R2;           // live only during CSR build

  unsigned* u1h = (unsigned*)R1;             // fp16 rm [n][64] (dead after pull-1)
  unsigned* g1h = (unsigned*)R2;             // fp16 rm [n][64] (dead after pull-2)
  float*    a2  = R2 + (size_t)32*n;         // f32 rm [n][64]  (dead after gemm23)
  float*    u3  = R1;                        // f32 [n][2]      (dead after pull2_lsm)

  const int BT = 256;

  k_zero <<<(nb+BT-1)/BT, BT, 0, stream>>>(bcnt, nb);
  k_bhist<<<(e+2047)/2048, BT, 0, stream>>>(col, bcnt, e, nb);
  k_bscan<<<1, NBMAX, 0, stream>>>(bcnt, bstart, bcursor, nb);
  k_part <<<(e+T1-1)/T1, 1024, 0, stream>>>(row, col, bcursor, pairs, e, nb);
  k_csr  <<<nb, BT, 0, stream>>>(pairs, bstart, bcnt, srcA, rowptr, dinv, n, e);

  k_gemm1<<<(n+63)/64, BT, 0, stream>>>(x, W1, dinv, u1h, n);

  const int pg = (n+3)/4;
  k_pullh<1><<<pg, BT, 0, stream>>>(srcA, rowptr, (const char*)u1h, dinv, b1, (void*)g1h, n);
  k_pullh<2><<<pg, BT, 0, stream>>>(srcA, rowptr, (const char*)g1h, dinv, nullptr, (void*)a2, n);

  k_gemm23<<<(n+63)/64, BT, 0, stream>>>(a2, W2, b2, W3, dinv, u3, n);
  k_pull2_lsm<<<(n+15)/16, BT, 0, stream>>>(srcA, rowptr, u3, dinv, b3, out, n);
}

// Round 12
// 179.124 us; speedup vs baseline: 1.1032x; 1.0063x over previous
//
#include <hip/hip_runtime.h>
#include <hip/hip_fp16.h>

constexpr int P  = 128;  // input features
constexpr int H  = 64;   // hidden 1
constexpr int H2 = 128;  // hidden 2
constexpr int C  = 2;    // classes

constexpr int BW_LOG = 7;        // bucket width = 128 destinations
constexpr int BWID   = 128;
constexpr int NBMAX  = 512;      // max buckets supported (n <= 65536)
constexpr int T1     = 8192;     // edges per partition block
constexpr int CAP2   = 15360;    // k_csr LDS staging capacity (ints)

__device__ __forceinline__ unsigned packh2(float a, float b){
  unsigned short la = __half_as_ushort(__float2half_rn(a));
  unsigned short lb = __half_as_ushort(__float2half_rn(b));
  return (unsigned)la | ((unsigned)lb << 16);
}

// ---------------- CSR build (two-level LDS-staged partition) ----------------
__global__ __launch_bounds__(256) void k_bhist(const int* __restrict__ col,
                                               int* __restrict__ bcnt, int e, int nb){
  __shared__ int h[NBMAX];
  for(int i=threadIdx.x;i<nb;i+=256) h[i]=0;
  __syncthreads();
  int b0 = blockIdx.x*2048;
  #pragma unroll
  for(int u=0;u<8;u++){
    int idx = b0 + u*256 + threadIdx.x;
    if(idx<e) atomicAdd(&h[col[idx]>>BW_LOG], 1);
  }
  __syncthreads();
  for(int i=threadIdx.x;i<nb;i+=256) if(h[i]) atomicAdd(&bcnt[i], h[i]);
}

__global__ __launch_bounds__(NBMAX) void k_bscan(const int* __restrict__ bcnt,
                                                 int* __restrict__ bstart,
                                                 int* __restrict__ bcursor, int nb){
  __shared__ int sm[NBMAX];
  int t = threadIdx.x;
  int v = (t<nb)? bcnt[t] : 0;
  sm[t]=v; __syncthreads();
  for(int d=1; d<NBMAX; d<<=1){
    int u = (t>=d)? sm[t-d] : 0;
    __syncthreads();
    sm[t]+=u;
    __syncthreads();
  }
  if(t<nb){ int s = sm[t]-v; bstart[t]=s; bcursor[t]=s; }
}

__global__ __launch_bounds__(1024) void k_part(const int* __restrict__ row,
                                               const int* __restrict__ col,
                                               int* __restrict__ bcursor,
                                               unsigned* __restrict__ pairs, int e, int nb){
  __shared__ unsigned stage[T1];
  __shared__ int hist[NBMAX];
  __shared__ int base[NBMAX];   // exclusive prefix of hist
  __shared__ int gpos[NBMAX];
  int tid = threadIdx.x;
  int e0 = blockIdx.x*T1;
  int cnt = min(T1, e-e0);
  for(int i=tid;i<NBMAX;i+=1024) hist[i]=0;
  __syncthreads();
  int myb[8]; int myrank[8]; unsigned mypack[8];
  #pragma unroll
  for(int u=0;u<8;u++){
    int idx = u*1024 + tid;
    if(idx<cnt){
      int c = col[e0+idx], r = row[e0+idx];
      int b = c>>BW_LOG;
      myb[u] = b;
      mypack[u] = ((unsigned)r<<BW_LOG) | (unsigned)(c & (BWID-1));
      myrank[u] = atomicAdd(&hist[b], 1);
    } else myb[u] = -1;
  }
  __syncthreads();
  // single-wave exclusive scan of hist[0..511] (lane covers 8 consecutive)
  if(tid<64){
    int v[8]; int sum=0;
    #pragma unroll
    for(int i=0;i<8;i++) v[i]=hist[tid*8+i];
    #pragma unroll
    for(int i=0;i<8;i++){ int t=v[i]; v[i]=sum; sum+=t; }
    int run=sum;
    #pragma unroll
    for(int d=1; d<64; d<<=1){ int u=__shfl_up(run,d); if(tid>=d) run+=u; }
    int excl = run - sum;
    #pragma unroll
    for(int i=0;i<8;i++) base[tid*8+i] = excl + v[i];
  }
  __syncthreads();
  if(tid<nb) gpos[tid] = atomicAdd(&bcursor[tid], hist[tid]);
  __syncthreads();
  #pragma unroll
  for(int u=0;u<8;u++){
    if(myb[u]>=0) stage[ base[myb[u]] + myrank[u] ] = mypack[u];
  }
  __syncthreads();
  int wave = tid>>6, lane = tid&63;
  for(int b=wave; b<nb; b+=16){
    int len = hist[b], lo = base[b], go = gpos[b];
    for(int k=lane; k<len; k+=64) pairs[go+k] = stage[lo+k];
  }
}

// stores srcA as BYTE offsets into the fp16 table: src_node*128 = pair & ~0x7F
__global__ __launch_bounds__(256) void k_csr(const unsigned* __restrict__ pairs,
                                             const int* __restrict__ bstart,
                                             const int* __restrict__ bcnt,
                                             unsigned* __restrict__ srcA,
                                             int* __restrict__ rowptr,
                                             float* __restrict__ dinv,
                                             int n, int e){
  __shared__ int hist[BWID];
  __shared__ int base[BWID];    // exclusive prefix
  __shared__ int cur[BWID];
  __shared__ unsigned stageS[CAP2];
  int b = blockIdx.x, tid = threadIdx.x;
  int lo = bstart[b], cnt = bcnt[b];
  if(tid<BWID) hist[tid]=0;
  __syncthreads();
  for(int i=tid;i<cnt;i+=256) atomicAdd(&hist[pairs[lo+i] & (BWID-1)], 1);
  __syncthreads();
  // single-wave exclusive scan of hist[0..127] (lane covers 2 consecutive)
  if(tid<64){
    int v0=hist[2*tid], v1=hist[2*tid+1];
    int sum=v0+v1;
    int run=sum;
    #pragma unroll
    for(int d=1; d<64; d<<=1){ int u=__shfl_up(run,d); if(tid>=d) run+=u; }
    int excl = run - sum;
    base[2*tid]   = excl;
    base[2*tid+1] = excl + v0;
  }
  __syncthreads();
  if(tid<BWID){
    int ex = base[tid];
    cur[tid] = ex;
    int node = (b<<BW_LOG) + tid;
    if(node<n){
      rowptr[node] = lo + ex;
      dinv[node]   = rsqrtf((float)hist[tid] + 1.0f);
    }
  }
  if(b==0 && tid==0) rowptr[n] = e;
  __syncthreads();
  if(cnt<=CAP2){
    for(int i=tid;i<cnt;i+=256){
      unsigned p = pairs[lo+i];
      int pos = atomicAdd(&cur[p & (BWID-1)], 1);
      stageS[pos] = p & ~0x7Fu;     // src_node*128 (byte offset)
    }
    __syncthreads();
    for(int i=tid;i<cnt;i+=256) srcA[lo+i] = stageS[i];
  } else {
    for(int i=tid;i<cnt;i+=256){
      unsigned p = pairs[lo+i];
      int pos = atomicAdd(&cur[p & (BWID-1)], 1);
      srcA[lo+pos] = p & ~0x7Fu;
    }
  }
}

// ---------------- GEMM1: tiled 64x64 -> fp16 row-major out [n][64] ----------------
__global__ __launch_bounds__(256) void k_gemm1(const float* __restrict__ x,
                                               const float* __restrict__ W,
                                               const float* __restrict__ dinv,
                                               unsigned* __restrict__ out, int n){
  __shared__ float xs[64][68];
  __shared__ float ws[64][64];
  int tid = threadIdx.x;
  int tx = tid & 15, ty = tid >> 4;
  int r0 = blockIdx.x*64;
  float acc[4][4] = {};
  const float4* x4 = (const float4*)x;
  const float4* W4 = (const float4*)W;
  for(int kh=0; kh<2; ++kh){
    __syncthreads();
    #pragma unroll
    for(int it=0; it<4; ++it){
      int idx = tid + 256*it;
      int r = idx >> 4, k4 = idx & 15;
      int gr = r0 + r;
      float4 v = (gr<n) ? x4[(size_t)gr*32 + kh*16 + k4] : make_float4(0.f,0.f,0.f,0.f);
      *(float4*)&xs[r][4*k4] = v;
    }
    #pragma unroll
    for(int it=0; it<4; ++it){
      int idx = tid + 256*it;
      int kk = idx >> 4, c4 = idx & 15;
      *(float4*)&ws[kk][4*c4] = W4[(size_t)(kh*64+kk)*16 + c4];
    }
    __syncthreads();
    #pragma unroll 8
    for(int kk=0; kk<64; ++kk){
      float xv0 = xs[4*ty+0][kk];
      float xv1 = xs[4*ty+1][kk];
      float xv2 = xs[4*ty+2][kk];
      float xv3 = xs[4*ty+3][kk];
      float4 wv = *(const float4*)&ws[kk][4*tx];
      acc[0][0] += xv0*wv.x; acc[0][1] += xv0*wv.y; acc[0][2] += xv0*wv.z; acc[0][3] += xv0*wv.w;
      acc[1][0] += xv1*wv.x; acc[1][1] += xv1*wv.y; acc[1][2] += xv1*wv.z; acc[1][3] += xv1*wv.w;
      acc[2][0] += xv2*wv.x; acc[2][1] += xv2*wv.y; acc[2][2] += xv2*wv.z; acc[2][3] += xv2*wv.w;
      acc[3][0] += xv3*wv.x; acc[3][1] += xv3*wv.y; acc[3][2] += xv3*wv.z; acc[3][3] += xv3*wv.w;
    }
  }
  // fp16 row-major write: row = 32 uints (64 halves); thread tx owns cols 4tx..4tx+3
  #pragma unroll
  for(int i=0;i<4;i++){
    int gr = r0 + 4*ty + i;
    if(gr<n){
      float d = dinv[gr];
      uint2 w;
      w.x = packh2(acc[i][0]*d, acc[i][1]*d);
      w.y = packh2(acc[i][2]*d, acc[i][3]*d);
      *(uint2*)&out[(size_t)gr*32 + 2*tx] = w;
    }
  }
}

// ---------------- GEMM2+GEMM3 fused (a2 fp16 row-major [n][64]) ----------------
__global__ __launch_bounds__(256) void k_gemm23(const unsigned* __restrict__ a2h,
                                                const float* __restrict__ W2,
                                                const float* __restrict__ b2,
                                                const float* __restrict__ W3,
                                                const float* __restrict__ dinv,
                                                float* __restrict__ u3, int n){
  __shared__ float as[64][68];
  __shared__ float ws[64][128];
  __shared__ float w3s[H2*C];
  __shared__ float b2s[H2];
  int tid = threadIdx.x;
  int tx = tid & 15, ty = tid >> 4;
  int r0 = blockIdx.x*64;
  const uint4* a16 = (const uint4*)a2h;   // 8 uint4 per row
  const float4* W24 = (const float4*)W2;
  #pragma unroll
  for(int it=0; it<2; ++it){
    int idx = tid + 256*it;        // 0..511
    int r = idx >> 3, u = idx & 7;
    int gr = r0 + r;
    uint4 v = (gr<n) ? a16[(size_t)gr*8 + u] : make_uint4(0,0,0,0);
    const __half2* hp = (const __half2*)&v;
    float2 f0=__half22float2(hp[0]), f1=__half22float2(hp[1]);
    float2 f2=__half22float2(hp[2]), f3=__half22float2(hp[3]);
    float* dst = &as[r][8*u];
    dst[0]=f0.x; dst[1]=f0.y; dst[2]=f1.x; dst[3]=f1.y;
    dst[4]=f2.x; dst[5]=f2.y; dst[6]=f3.x; dst[7]=f3.y;
  }
  #pragma unroll
  for(int it=0; it<8; ++it){
    int idx = tid + 256*it;
    int kk = idx >> 5, c4 = idx & 31;
    *(float4*)&ws[kk][4*c4] = W24[(size_t)kk*32 + c4];
  }
  if(tid < H2*C) w3s[tid] = W3[tid];
  if(tid < H2)   b2s[tid] = b2[tid];
  __syncthreads();
  float acc[4][8] = {};
  #pragma unroll 4
  for(int kk=0; kk<64; ++kk){
    float xv0 = as[4*ty+0][kk];
    float xv1 = as[4*ty+1][kk];
    float xv2 = as[4*ty+2][kk];
    float xv3 = as[4*ty+3][kk];
    float4 wa = *(const float4*)&ws[kk][8*tx];
    float4 wb = *(const float4*)&ws[kk][8*tx+4];
    acc[0][0]+=xv0*wa.x; acc[0][1]+=xv0*wa.y; acc[0][2]+=xv0*wa.z; acc[0][3]+=xv0*wa.w;
    acc[0][4]+=xv0*wb.x; acc[0][5]+=xv0*wb.y; acc[0][6]+=xv0*wb.z; acc[0][7]+=xv0*wb.w;
    acc[1][0]+=xv1*wa.x; acc[1][1]+=xv1*wa.y; acc[1][2]+=xv1*wa.z; acc[1][3]+=xv1*wa.w;
    acc[1][4]+=xv1*wb.x; acc[1][5]+=xv1*wb.y; acc[1][6]+=xv1*wb.z; acc[1][7]+=xv1*wb.w;
    acc[2][0]+=xv2*wa.x; acc[2][1]+=xv2*wa.y; acc[2][2]+=xv2*wa.z; acc[2][3]+=xv2*wa.w;
    acc[2][4]+=xv2*wb.x; acc[2][5]+=xv2*wb.y; acc[2][6]+=xv2*wb.z; acc[2][7]+=xv2*wb.w;
    acc[3][0]+=xv3*wa.x; acc[3][1]+=xv3*wa.y; acc[3][2]+=xv3*wa.z; acc[3][3]+=xv3*wa.w;
    acc[3][4]+=xv3*wb.x; acc[3][5]+=xv3*wb.y; acc[3][6]+=xv3*wb.z; acc[3][7]+=xv3*wb.w;
  }
  float p[4][2] = {};
  #pragma unroll
  for(int j=0;j<8;j++){
    int c = 8*tx + j;
    float w30 = w3s[2*c], w31 = w3s[2*c+1], bb = b2s[c];
    #pragma unroll
    for(int i=0;i<4;i++){
      float g = fmaxf(acc[i][j] + bb, 0.f);
      p[i][0] += g*w30;
      p[i][1] += g*w31;
    }
  }
  #pragma unroll
  for(int d=1; d<16; d<<=1){
    #pragma unroll
    for(int i=0;i<4;i++){
      p[i][0] += __shfl_xor(p[i][0], d);
      p[i][1] += __shfl_xor(p[i][1], d);
    }
  }
  if(tx==0){
    #pragma unroll
    for(int i=0;i<4;i++){
      int gr = r0 + 4*ty + i;
      if(gr<n){
        float d = dinv[gr];
        u3[2*gr]   = d*p[i][0];
        u3[2*gr+1] = d*p[i][1];
      }
    }
  }
}

// ---------------- merged fp16 pull: wave per node, 8 edge-slots x 8 lanes x 16B ----------------
// table fp16 row-major [n][64] (128B rows). srcA = byte offsets (src*128).
// MODE 1: g1h(fp16 rm) = dinv*relu(dinv*sum + bias)   MODE 2: a2h(fp16 rm) = dinv*sum
template<int MODE>
__global__ __launch_bounds__(256) void k_pullh(const unsigned* __restrict__ src,
                                               const int* __restrict__ rowptr,
                                               const char* __restrict__ tb0,
                                               const float* __restrict__ dinv,
                                               const float* __restrict__ bias,
                                               unsigned* __restrict__ outp, int n){
  int node = blockIdx.x*4 + (threadIdx.x>>6);
  if(node>=n) return;
  int lane = threadIdx.x & 63;
  int slot = lane >> 3;      // edge slot 0..7
  int q    = lane & 7;       // 16B quad within 128B row
  const char* tb = tb0 + q*16;   // per-lane base; gather addr = tb + srcByteOff
  __half2 h0 = __float2half2_rn(0.f), h1 = h0, h2v = h0, h3 = h0;
  __half2 g0 = h0, g1 = h0, g2v = h0, g3 = h0;
  int beg = rowptr[node], end = rowptr[node+1];
  int j = beg;
  for(; j+32<=end; j+=32){   // 4 independent gathers in flight
    unsigned s0 = src[j+slot],    s1 = src[j+8+slot];
    unsigned s2 = src[j+16+slot], s3 = src[j+24+slot];
    uint4 r0 = *(const uint4*)(tb + s0);
    uint4 r1 = *(const uint4*)(tb + s1);
    uint4 r2 = *(const uint4*)(tb + s2);
    uint4 r3 = *(const uint4*)(tb + s3);
    const __half2* p0 = (const __half2*)&r0;
    const __half2* p1 = (const __half2*)&r1;
    const __half2* p2 = (const __half2*)&r2;
    const __half2* p3 = (const __half2*)&r3;
    h0 = __hadd2(h0, p0[0]); h1 = __hadd2(h1, p0[1]);
    h2v= __hadd2(h2v,p0[2]); h3 = __hadd2(h3, p0[3]);
    g0 = __hadd2(g0, p1[0]); g1 = __hadd2(g1, p1[1]);
    g2v= __hadd2(g2v,p1[2]); g3 = __hadd2(g3, p1[3]);
    h0 = __hadd2(h0, p2[0]); h1 = __hadd2(h1, p2[1]);
    h2v= __hadd2(h2v,p2[2]); h3 = __hadd2(h3, p2[3]);
    g0 = __hadd2(g0, p3[0]); g1 = __hadd2(g1, p3[1]);
    g2v= __hadd2(g2v,p3[2]); g3 = __hadd2(g3, p3[3]);
  }
  for(; j+16<=end; j+=16){
    unsigned s0 = src[j+slot], s1 = src[j+8+slot];
    uint4 r0 = *(const uint4*)(tb + s0);
    uint4 r1 = *(const uint4*)(tb + s1);
    const __half2* p0 = (const __half2*)&r0;
    const __half2* p1 = (const __half2*)&r1;
    h0 = __hadd2(h0, p0[0]); h1 = __hadd2(h1, p0[1]);
    h2v= __hadd2(h2v,p0[2]); h3 = __hadd2(h3, p0[3]);
    g0 = __hadd2(g0, p1[0]); g1 = __hadd2(g1, p1[1]);
    g2v= __hadd2(g2v,p1[2]); g3 = __hadd2(g3, p1[3]);
  }
  for(; j+8<=end; j+=8){
    unsigned s = src[j+slot];
    uint4 r = *(const uint4*)(tb + s);
    const __half2* p = (const __half2*)&r;
    h0 = __hadd2(h0, p[0]); h1 = __hadd2(h1, p[1]);
    h2v= __hadd2(h2v,p[2]); h3 = __hadd2(h3, p[3]);
  }
  if(j+slot < end){
    unsigned s = src[j+slot];
    uint4 r = *(const uint4*)(tb + s);
    const __half2* p = (const __half2*)&r;
    g0 = __hadd2(g0, p[0]); g1 = __hadd2(g1, p[1]);
    g2v= __hadd2(g2v,p[2]); g3 = __hadd2(g3, p[3]);
  }
  // combine banks in f32
  float a[8];
  {
    float2 fa, fb;
    fa = __half22float2(h0); fb = __half22float2(g0); a[0]=fa.x+fb.x; a[1]=fa.y+fb.y;
    fa = __half22float2(h1); fb = __half22float2(g1); a[2]=fa.x+fb.x; a[3]=fa.y+fb.y;
    fa = __half22float2(h2v);fb = __half22float2(g2v);a[4]=fa.x+fb.x; a[5]=fa.y+fb.y;
    fa = __half22float2(h3); fb = __half22float2(g3); a[6]=fa.x+fb.x; a[7]=fa.y+fb.y;
  }
  // reduce over slot bits (lane bits 3..5)
  #pragma unroll
  for(int d=8; d<64; d<<=1){
    #pragma unroll
    for(int i=0;i<8;i++) a[i] += __shfl_xor(a[i], d);
  }
  if(slot==0){
    uint4 sr = *(const uint4*)(tb + (unsigned)node*128u);   // self-loop row
    const __half2* p = (const __half2*)&sr;
    float2 f0 = __half22float2(p[0]), f1 = __half22float2(p[1]);
    float2 f2 = __half22float2(p[2]), f3 = __half22float2(p[3]);
    a[0]+=f0.x; a[1]+=f0.y; a[2]+=f1.x; a[3]+=f1.y;
    a[4]+=f2.x; a[5]+=f2.y; a[6]+=f3.x; a[7]+=f3.y;
    float dv = dinv[node];
    uint4 w;
    if(MODE==1){
      const float* bq = bias + 8*q;   // lane q covers features 8q..8q+7
      float o[8];
      #pragma unroll
      for(int i=0;i<8;i++) o[i] = dv * fmaxf(dv*a[i] + bq[i], 0.f);
      w.x = packh2(o[0],o[1]); w.y = packh2(o[2],o[3]);
      w.z = packh2(o[4],o[5]); w.w = packh2(o[6],o[7]);
    } else {
      w.x = packh2(dv*a[0], dv*a[1]); w.y = packh2(dv*a[2], dv*a[3]);
      w.z = packh2(dv*a[4], dv*a[5]); w.w = packh2(dv*a[6], dv*a[7]);
    }
    ((uint4*)outp)[(size_t)node*8 + q] = w;
  }
}

// F=2 pull + bias + log_softmax fused; 4 nodes per wave (16 lanes each)
__global__ __launch_bounds__(256) void k_pull2_lsm(const unsigned* __restrict__ src,
                                                   const int* __restrict__ rowptr,
                                                   const float* __restrict__ u3,
                                                   const float* __restrict__ dinv,
                                                   const float* __restrict__ b3,
                                                   float* __restrict__ out, int n){
  int node = blockIdx.x*16 + (threadIdx.x>>4);
  int l16  = threadIdx.x & 15;
  if(node>=n) return;
  const char* ub = (const char*)u3;
  int beg = rowptr[node], end = rowptr[node+1];
  float p0=0.f, p1=0.f, q0=0.f, q1=0.f;
  int j = beg + l16;
  for(; j+16 < end; j += 32){
    float2 A = *(const float2*)(ub + (src[j]    >> 4));
    float2 B = *(const float2*)(ub + (src[j+16] >> 4));
    p0 += A.x; p1 += A.y; q0 += B.x; q1 += B.y;
  }
  if(j < end){
    float2 A = *(const float2*)(ub + (src[j] >> 4));
    p0 += A.x; p1 += A.y;
  }
  p0 += q0; p1 += q1;
  #pragma unroll
  for(int d=1; d<16; d<<=1){ p0 += __shfl_xor(p0,d); p1 += __shfl_xor(p1,d); }
  if(l16==0){
    float d = dinv[node];
    const float2 self = *(const float2*)(ub + (size_t)node*8);
    float z0 = d*(p0 + self.x) + b3[0];
    float z1 = d*(p1 + self.y) + b3[1];
    float m = fmaxf(z0,z1);
    float l = m + logf(expf(z0-m)+expf(z1-m));
    out[2*node]   = z0-l;
    out[2*node+1] = z1-l;
  }
}

extern "C" void kernel_launch(void* const* d_in, const int* in_sizes, int n_in,
                              void* d_out, int out_size, void* d_ws, size_t ws_size,
                              hipStream_t stream){
  const float* x  = (const float*)d_in[0];
  const int*   ei = (const int*)  d_in[1];
  const float* W1 = (const float*)d_in[2];
  const float* b1 = (const float*)d_in[3];
  const float* W2 = (const float*)d_in[4];
  const float* b2 = (const float*)d_in[5];
  const float* W3 = (const float*)d_in[6];
  const float* b3 = (const float*)d_in[7];
  float* out = (float*)d_out;

  const int n = in_sizes[0] / P;       // 50000
  const int e = in_sizes[1] / 2;       // 1600000
  const int* row = ei;
  const int* col = ei + e;
  const int nb = (n + BWID - 1) >> BW_LOG;

  float* ws   = (float*)d_ws;
  size_t off = 0;
  float* dinv = ws + off; off += n;
  float* R1   = ws + off; off += (size_t)64*n;
  float* R2   = ws + off; off += (size_t)128*n;
  int* rowptr = (int*)(ws + off); off += n+1;
  unsigned* srcA = (unsigned*)(ws + off); off += e;
  int* bcnt   = (int*)(ws + off); off += NBMAX;
  int* bstart = (int*)(ws + off); off += NBMAX;
  int* bcursor= (int*)(ws + off); off += NBMAX;

  unsigned* pairs = (unsigned*)R2;           // live only during CSR build

  unsigned* u1h = (unsigned*)R1;             // fp16 rm [n][64] (dead after pull-1)
  unsigned* g1h = (unsigned*)R2;             // fp16 rm [n][64] (dead after pull-2)
  unsigned* a2h = (unsigned*)R1;             // fp16 rm [n][64] (dead after gemm23; reuses u1h space)
  float*    u3  = R1 + (size_t)32*n;         // f32 [n][2]      (no alias with a2h)

  const int BT = 256;

  hipMemsetAsync(bcnt, 0, NBMAX*sizeof(int), stream);
  k_bhist<<<(e+2047)/2048, BT, 0, stream>>>(col, bcnt, e, nb);
  k_bscan<<<1, NBMAX, 0, stream>>>(bcnt, bstart, bcursor, nb);
  k_part <<<(e+T1-1)/T1, 1024, 0, stream>>>(row, col, bcursor, pairs, e, nb);
  k_csr  <<<nb, BT, 0, stream>>>(pairs, bstart, bcnt, srcA, rowptr, dinv, n, e);

  k_gemm1<<<(n+63)/64, BT, 0, stream>>>(x, W1, dinv, u1h, n);

  const int pg = (n+3)/4;
  k_pullh<1><<<pg, BT, 0, stream>>>(srcA, rowptr, (const char*)u1h, dinv, b1, g1h, n);
  k_pullh<2><<<pg, BT, 0, stream>>>(srcA, rowptr, (const char*)g1h, dinv, nullptr, a2h, n);

  k_gemm23<<<(n+63)/64, BT, 0, stream>>>(a2h, W2, b2, W3, dinv, u3, n);
  k_pull2_lsm<<<(n+15)/16, BT, 0, stream>>>(srcA, rowptr, u3, dinv, b3, out, n);
}